// Round 2
// baseline (1076.984 us; speedup 1.0000x reference)
//
#include <hip/hip_runtime.h>
#include <hip/hip_bf16.h>

#define N_NODES 100000
#define N_EDGES 3200000
#define IN_DIM  29
#define HID_DIM 64
#define OUT_DIM 2

// ---------------- degree (in-degree over dst, self-loop added later) --------
__global__ void deg_kernel(const int* __restrict__ dst, float* __restrict__ deg) {
    int i = blockIdx.x * blockDim.x + threadIdx.x;
    if (i < N_EDGES) atomicAdd(&deg[dst[i]], 1.0f);
}

// deg -> dinv in place; +1.0 is the self loop, so deg>0 always
__global__ void dinv_kernel(float* __restrict__ deg) {
    int i = blockIdx.x * blockDim.x + threadIdx.x;
    if (i < N_NODES) deg[i] = rsqrtf(deg[i] + 1.0f);
}

// ---------------- layer-1 edge aggregation of raw x (29 dims) ---------------
// 32 threads (half-wave) per edge; lane k<29 handles feature k.
__global__ void scatter1_kernel(const int* __restrict__ ei,
                                const float* __restrict__ x,
                                const float* __restrict__ dinv,
                                float* __restrict__ aggX) {
    long long t = (long long)blockIdx.x * blockDim.x + threadIdx.x;
    int e    = (int)(t >> 5);
    int lane = (int)(t & 31);
    if (e >= N_EDGES) return;
    int s = ei[e];
    int d = ei[N_EDGES + e];
    float n = dinv[s] * dinv[d];
    if (lane < IN_DIM) {
        float v = x[s * IN_DIM + lane] * n;
        atomicAdd(&aggX[d * IN_DIM + lane], v);
    }
}

// ---------------- fused node transform: relu((aggX + self)@W1 + b1) @ W2 ----
// one wave per node; lane j owns hidden unit j; shuffle-reduce to z[2]
__global__ __launch_bounds__(256) void transform_kernel(
        const float* __restrict__ aggX,
        const float* __restrict__ x,
        const float* __restrict__ dinv,
        const float* __restrict__ W1,
        const float* __restrict__ b1,
        const float* __restrict__ W2,
        float* __restrict__ z) {
    __shared__ float w1s[IN_DIM * HID_DIM];
    __shared__ float w2s[HID_DIM * OUT_DIM];
    int tid = threadIdx.x;
    for (int k = tid; k < IN_DIM * HID_DIM; k += blockDim.x)
        w1s[k] = W1[k];
    for (int k = tid; k < HID_DIM * OUT_DIM; k += blockDim.x)
        w2s[k] = W2[k];
    __syncthreads();

    int wave = tid >> 6;
    int lane = tid & 63;
    int node = blockIdx.x * 4 + wave;
    if (node >= N_NODES) return;

    float di = dinv[node];
    float d2 = di * di;   // self-loop norm = dinv[i]*dinv[i]

    float h = b1[lane];
    #pragma unroll
    for (int k = 0; k < IN_DIM; ++k) {
        float a = aggX[node * IN_DIM + k] + x[node * IN_DIM + k] * d2;
        h = fmaf(a, w1s[k * HID_DIM + lane], h);
    }
    h = fmaxf(h, 0.0f);

    float z0 = h * w2s[lane * OUT_DIM + 0];
    float z1 = h * w2s[lane * OUT_DIM + 1];
    #pragma unroll
    for (int off = 32; off > 0; off >>= 1) {
        z0 += __shfl_down(z0, off);
        z1 += __shfl_down(z1, off);
    }
    if (lane == 0) {
        z[node * 2 + 0] = z0;
        z[node * 2 + 1] = z1;
    }
}

// ---------------- layer-2 edge aggregation of z (2 dims) --------------------
__global__ void scatter2_kernel(const int* __restrict__ ei,
                                const float* __restrict__ z,
                                const float* __restrict__ dinv,
                                float* __restrict__ outAgg) {
    int e = blockIdx.x * blockDim.x + threadIdx.x;
    if (e >= N_EDGES) return;
    int s = ei[e];
    int d = ei[N_EDGES + e];
    float n = dinv[s] * dinv[d];
    atomicAdd(&outAgg[d * 2 + 0], z[s * 2 + 0] * n);
    atomicAdd(&outAgg[d * 2 + 1], z[s * 2 + 1] * n);
}

// ---------------- finalize: + self-loop + b2 --------------------------------
__global__ void finalize_kernel(const float* __restrict__ outAgg,
                                const float* __restrict__ z,
                                const float* __restrict__ dinv,
                                const float* __restrict__ b2,
                                float* __restrict__ out) {
    int i = blockIdx.x * blockDim.x + threadIdx.x;
    if (i >= N_NODES) return;
    float d2 = dinv[i] * dinv[i];
    out[i * 2 + 0] = outAgg[i * 2 + 0] + z[i * 2 + 0] * d2 + b2[0];
    out[i * 2 + 1] = outAgg[i * 2 + 1] + z[i * 2 + 1] * d2 + b2[1];
}

extern "C" void kernel_launch(void* const* d_in, const int* in_sizes, int n_in,
                              void* d_out, int out_size, void* d_ws, size_t ws_size,
                              hipStream_t stream) {
    const float* x  = (const float*)d_in[0];
    const int*   ei = (const int*)d_in[1];
    const float* W1 = (const float*)d_in[2];
    const float* b1 = (const float*)d_in[3];
    const float* W2 = (const float*)d_in[4];
    const float* b2 = (const float*)d_in[5];
    float* out = (float*)d_out;

    float* ws     = (float*)d_ws;
    float* deg    = ws;                    // N    (becomes dinv in place)
    float* aggX   = ws + N_NODES;          // 29N
    float* outAgg = ws + 30 * N_NODES;     // 2N
    float* z      = ws + 32 * N_NODES;     // 2N  (fully written, no zeroing)

    // zero deg | aggX | outAgg in one contiguous memset (32N floats)
    hipMemsetAsync(ws, 0, (size_t)32 * N_NODES * sizeof(float), stream);

    deg_kernel<<<(N_EDGES + 255) / 256, 256, 0, stream>>>(ei + N_EDGES, deg);
    dinv_kernel<<<(N_NODES + 255) / 256, 256, 0, stream>>>(deg);

    long long s1_threads = (long long)N_EDGES * 32;
    scatter1_kernel<<<(int)((s1_threads + 255) / 256), 256, 0, stream>>>(ei, x, deg, aggX);

    transform_kernel<<<(N_NODES + 3) / 4, 256, 0, stream>>>(aggX, x, deg, W1, b1, W2, z);

    scatter2_kernel<<<(N_EDGES + 255) / 256, 256, 0, stream>>>(ei, z, deg, outAgg);

    finalize_kernel<<<(N_NODES + 255) / 256, 256, 0, stream>>>(outAgg, z, deg, b2, out);
}

// Round 3
// 694.269 us; speedup vs baseline: 1.5512x; 1.5512x over previous
//
#include <hip/hip_runtime.h>

#define N_NODES 100000
#define N_EDGES 3200000
#define IN_DIM  29
#define PAD_DIM 32
#define HID_DIM 64
#define OUT_DIM 2
#define SCAN_B  1024
#define NB      ((N_NODES + SCAN_B - 1) / SCAN_B)   // 98

// ---- ws layout (units of 4 bytes) -----------------------------------------
// hist[N] | rowStart[N+1] | cursor[N] | part[NB] | dinv[N] | zs[2N] | esrc[E] | xs[32N]
#define OFF_HIST   0
#define OFF_ROWS   100032
#define OFF_CURSOR 200064
#define OFF_PART   300064
#define OFF_DINV   300192
#define OFF_ZS     400192
#define OFF_ESRC   600192
#define OFF_XS     3800192
// total 7,000,192 floats = 28.0 MB

// ---------------- in-degree histogram over dst (int atomics) ---------------
__global__ void hist_kernel(const int* __restrict__ dst, int* __restrict__ hist) {
    int i = blockIdx.x * blockDim.x + threadIdx.x;
    if (i < N_EDGES) atomicAdd(&hist[dst[i]], 1);
}

// ---------------- scan phase A: per-block sums ------------------------------
__global__ __launch_bounds__(SCAN_B) void scanA_kernel(const int* __restrict__ hist,
                                                       int* __restrict__ part) {
    __shared__ int s[SCAN_B];
    int idx = blockIdx.x * SCAN_B + threadIdx.x;
    s[threadIdx.x] = (idx < N_NODES) ? hist[idx] : 0;
    __syncthreads();
    for (int off = SCAN_B / 2; off > 0; off >>= 1) {
        if (threadIdx.x < off) s[threadIdx.x] += s[threadIdx.x + off];
        __syncthreads();
    }
    if (threadIdx.x == 0) part[blockIdx.x] = s[0];
}

// ---------------- scan phase B: exclusive scan of 98 partials ---------------
__global__ void scanB_kernel(int* __restrict__ part, int* __restrict__ rowStart) {
    if (threadIdx.x == 0) {
        int run = 0;
        for (int i = 0; i < NB; ++i) { int t = part[i]; part[i] = run; run += t; }
        rowStart[N_NODES] = N_EDGES;
    }
}

// ---------------- scan phase C: rowStart/cursor/dinv ------------------------
__global__ __launch_bounds__(SCAN_B) void scanC_kernel(const int* __restrict__ hist,
        const int* __restrict__ part, int* __restrict__ rowStart,
        int* __restrict__ cursor, float* __restrict__ dinv) {
    __shared__ int s[SCAN_B];
    int idx = blockIdx.x * SCAN_B + threadIdx.x;
    int v = (idx < N_NODES) ? hist[idx] : 0;
    s[threadIdx.x] = v;
    __syncthreads();
    for (int off = 1; off < SCAN_B; off <<= 1) {           // Hillis-Steele inclusive
        int t = (threadIdx.x >= off) ? s[threadIdx.x - off] : 0;
        __syncthreads();
        s[threadIdx.x] += t;
        __syncthreads();
    }
    if (idx < N_NODES) {
        int excl = s[threadIdx.x] - v + part[blockIdx.x];
        rowStart[idx] = excl;
        cursor[idx]   = excl;
        dinv[idx]     = rsqrtf((float)v + 1.0f);           // +1 = self loop
    }
}

// ---------------- xs = x * dinv[src], padded to 32 floats/node --------------
__global__ void xs_kernel(const float* __restrict__ x, const float* __restrict__ dinv,
                          float* __restrict__ xs) {
    int i = blockIdx.x * blockDim.x + threadIdx.x;         // over N*32
    if (i >= N_NODES * PAD_DIM) return;
    int n = i >> 5, k = i & 31;
    xs[i] = (k < IN_DIM) ? x[n * IN_DIM + k] * dinv[n] : 0.0f;
}

// ---------------- CSR fill: counting-sort placement -------------------------
__global__ void fill_kernel(const int* __restrict__ ei, int* __restrict__ cursor,
                            int* __restrict__ esrc) {
    int e = blockIdx.x * blockDim.x + threadIdx.x;
    if (e >= N_EDGES) return;
    int d = ei[N_EDGES + e];
    int pos = atomicAdd(&cursor[d], 1);
    esrc[pos] = ei[e];
}

// ------- fused: gather-aggregate xs -> W1 -> relu -> W2 -> zs (per node) ----
// one wave per node; two half-waves each own an edge stream; lane k<32 = feature k
__global__ __launch_bounds__(256) void fused_kernel(const float* __restrict__ xs,
        const int* __restrict__ rowStart, const int* __restrict__ esrc,
        const float* __restrict__ dinv,
        const float* __restrict__ W1, const float* __restrict__ b1,
        const float* __restrict__ W2, float* __restrict__ zs) {
    __shared__ float w1s[IN_DIM * HID_DIM];
    __shared__ float w2s[HID_DIM * OUT_DIM];
    int tid = threadIdx.x;
    for (int i = tid; i < IN_DIM * HID_DIM; i += 256) w1s[i] = W1[i];
    for (int i = tid; i < HID_DIM * OUT_DIM; i += 256) w2s[i] = W2[i];
    __syncthreads();

    int lane = tid & 63;
    int node = blockIdx.x * 4 + (tid >> 6);
    if (node >= N_NODES) return;

    int half = lane >> 5;
    int k    = lane & 31;
    int rs = rowStart[node], re = rowStart[node + 1];

    // self-loop term (xs[node] already has one dinv factor) in half 0
    float acc = half ? 0.0f : xs[node * PAD_DIM + k];
    for (int j = rs + half; j < re; j += 2) {
        int s = esrc[j];
        acc += xs[s * PAD_DIM + k];                        // 128B coalesced line
    }
    acc += __shfl_down(acc, 32);                           // fold halves
    float dn = dinv[node];
    acc *= dn;                                             // lanes 0..28 hold a_k

    float h = b1[lane];
    #pragma unroll
    for (int kk = 0; kk < IN_DIM; ++kk)
        h = fmaf(__shfl(acc, kk), w1s[kk * HID_DIM + lane], h);
    h = fmaxf(h, 0.0f);

    float z0 = h * w2s[lane * OUT_DIM + 0];
    float z1 = h * w2s[lane * OUT_DIM + 1];
    #pragma unroll
    for (int off = 32; off > 0; off >>= 1) {
        z0 += __shfl_down(z0, off);
        z1 += __shfl_down(z1, off);
    }
    if (lane == 0) {                                       // pre-scale by src dinv
        zs[node * 2 + 0] = z0 * dn;
        zs[node * 2 + 1] = z1 * dn;
    }
}

// ---------------- layer-2 gather of zs + finalize ---------------------------
__global__ __launch_bounds__(256) void agg2_kernel(const float* __restrict__ zs,
        const int* __restrict__ rowStart, const int* __restrict__ esrc,
        const float* __restrict__ dinv, const float* __restrict__ b2,
        float* __restrict__ out) {
    int lane = threadIdx.x & 63;
    int node = blockIdx.x * 4 + (threadIdx.x >> 6);
    if (node >= N_NODES) return;
    int rs = rowStart[node], re = rowStart[node + 1];
    float a0 = 0.0f, a1 = 0.0f;
    for (int j = rs + lane; j < re; j += 64) {
        int s = esrc[j];
        a0 += zs[s * 2 + 0];
        a1 += zs[s * 2 + 1];
    }
    #pragma unroll
    for (int off = 32; off > 0; off >>= 1) {
        a0 += __shfl_down(a0, off);
        a1 += __shfl_down(a1, off);
    }
    if (lane == 0) {
        float dn = dinv[node];
        out[node * 2 + 0] = dn * (a0 + zs[node * 2 + 0]) + b2[0];
        out[node * 2 + 1] = dn * (a1 + zs[node * 2 + 1]) + b2[1];
    }
}

extern "C" void kernel_launch(void* const* d_in, const int* in_sizes, int n_in,
                              void* d_out, int out_size, void* d_ws, size_t ws_size,
                              hipStream_t stream) {
    const float* x  = (const float*)d_in[0];
    const int*   ei = (const int*)d_in[1];
    const float* W1 = (const float*)d_in[2];
    const float* b1 = (const float*)d_in[3];
    const float* W2 = (const float*)d_in[4];
    const float* b2 = (const float*)d_in[5];
    float* out = (float*)d_out;

    int*   wsi      = (int*)d_ws;
    float* wsf      = (float*)d_ws;
    int*   hist     = wsi + OFF_HIST;
    int*   rowStart = wsi + OFF_ROWS;
    int*   cursor   = wsi + OFF_CURSOR;
    int*   part     = wsi + OFF_PART;
    float* dinv     = wsf + OFF_DINV;
    float* zs       = wsf + OFF_ZS;
    int*   esrc     = wsi + OFF_ESRC;
    float* xs       = wsf + OFF_XS;

    hipMemsetAsync(hist, 0, N_NODES * sizeof(int), stream);

    hist_kernel<<<(N_EDGES + 255) / 256, 256, 0, stream>>>(ei + N_EDGES, hist);
    scanA_kernel<<<NB, SCAN_B, 0, stream>>>(hist, part);
    scanB_kernel<<<1, 64, 0, stream>>>(part, rowStart);
    scanC_kernel<<<NB, SCAN_B, 0, stream>>>(hist, part, rowStart, cursor, dinv);
    xs_kernel<<<(N_NODES * PAD_DIM + 255) / 256, 256, 0, stream>>>(x, dinv, xs);
    fill_kernel<<<(N_EDGES + 255) / 256, 256, 0, stream>>>(ei, cursor, esrc);
    fused_kernel<<<(N_NODES + 3) / 4, 256, 0, stream>>>(xs, rowStart, esrc, dinv, W1, b1, W2, zs);
    agg2_kernel<<<(N_NODES + 3) / 4, 256, 0, stream>>>(zs, rowStart, esrc, dinv, b2, out);
}